// Round 4
// baseline (630.728 us; speedup 1.0000x reference)
//
#include <hip/hip_runtime.h>

// Problem: B=4, N_FRAMES=32 -> BN=128 samples; C=256, S=16 -> 256 spatial;
// TOKEN=65536; D=512.  softmax over size-1 axis == 1 => Wq/bq/Wk/bk are dead.
//
// Runtime dtype adaptivity: probe = gn_g (all ones).
//   f32 buffer:  first u32 == 0x3F800000
//   bf16 buffer: first u32 == 0x3F803F80
// All kernels branch (wave-uniform) on this; output dtype follows the same flag.

typedef unsigned short u16;
typedef unsigned int u32;
typedef __attribute__((ext_vector_type(8))) short short8;   // 8 bf16 (4 VGPRs)
typedef __attribute__((ext_vector_type(4))) float floatx4;  // MFMA C/D frag

__device__ __forceinline__ float b2f(u16 h){ return __uint_as_float(((u32)h)<<16); }
__device__ __forceinline__ u16 f2b(float f){
  u32 u = __float_as_uint(f);
  u = (u + 0x7FFFu + ((u>>16)&1u)) >> 16;   // RNE
  return (u16)u;
}
// Packed RNE f32x2 -> bf16x2 (dst.lo = bf16(lo), dst.hi = bf16(hi)).
// Non-volatile: pure value op, scheduler retains freedom.
__device__ __forceinline__ u32 cvtpk(float lo, float hi){
  u32 r;
  asm("v_cvt_pk_bf16_f32 %0, %1, %2" : "=v"(r) : "v"(lo), "v"(hi));
  return r;
}
__device__ __forceinline__ float blo(u32 w){ return __uint_as_float(w<<16); }
__device__ __forceinline__ float bhi(u32 w){ return __uint_as_float(w & 0xFFFF0000u); }
__device__ __forceinline__ bool probe_f32(const u32* p){ return p[0]==0x3F800000u; }

__device__ __forceinline__ float wred(float v){
  #pragma unroll
  for (int o=32;o>0;o>>=1) v += __shfl_down(v, o, 64);
  return v;
}

__device__ __forceinline__ float dot8(uint4 u, const float* t){
  return t[0]*blo(u.x)+t[1]*bhi(u.x)+t[2]*blo(u.y)+t[3]*bhi(u.y)
       + t[4]*blo(u.z)+t[5]*bhi(u.z)+t[6]*blo(u.w)+t[7]*bhi(u.w);
}

// Raw s_barrier WITHOUT the compiler's vmcnt(0) drain (__syncthreads drains all
// counters, killing register prefetch). ds_write visibility needs lgkmcnt(0) only.
// Compiler fences (zero-cost) prevent LLVM scheduling memory ops across the
// barrier; sched_barrier(0) after the asm waitcnt per guide rule #18.
__device__ __forceinline__ void bar_lgkm(){
  asm volatile("s_waitcnt lgkmcnt(0)" ::: "memory");
  __builtin_amdgcn_sched_barrier(0);
  __builtin_amdgcn_s_barrier();
  asm volatile("" ::: "memory");
}

// ---------------------------------------------------------------------------
// Convert the 22 small input tensors to a canonical bf16 region in ws.
// ---------------------------------------------------------------------------
struct SrcTab { const void* p[22]; };

__global__ __launch_bounds__(256) void cvt_k(SrcTab st, const u32* probe, u16* dst){
  constexpr int ns[22]   = {262144,262144,65536,589824,65536,65536,65536,65536,65536,
                            65536,512,512,512,512,512,256,2304,256,256,256,256,256};
  constexpr int offs[22] = {0,262144,524288,589824,1179648,1245184,1310720,1376256,1441792,
                            1507328,1572864,1573376,1573888,1574400,1574912,1575424,1575680,
                            1577984,1578240,1578496,1578752,1579008};
  int t = blockIdx.y;
  int e = (blockIdx.x*256 + threadIdx.x)*4;
  if (e >= ns[t]) return;
  u16* d = dst + offs[t] + e;
  if (probe_f32(probe)){
    float4 v = *(const float4*)((const float*)st.p[t] + e);
    d[0]=f2b(v.x); d[1]=f2b(v.y); d[2]=f2b(v.z); d[3]=f2b(v.w);
  } else {
    *(uint2*)d = *(const uint2*)((const u16*)st.p[t] + e);
  }
}

// ---------------------------------------------------------------------------
// 64x64-tile MFMA GEMM (NT): C[m][n] = sum_k A[m][k]*B[n][k] (+epilogue)
// Pipelined: register 2-deep global prefetch (refill-after-consume => ~2
// sub-iters of latency cover) + LDS ping-pong (ONE barrier per sub-iter).
// MODE 0: epilogue atomicAdd into fp32 C (split-K over gridDim.z)
// MODE 1: C_bf16 = acc + bias[n]
// MODE 3: A = bf16 with fused GroupNorm-normalize at staging; C_bf16 = relu(acc+bias)
// MODE 4: C_bf16 = acc + bias[n] + fres (bf16 residual, (n,c,s) layout)
// araw/braw: operand is a RAW input buffer whose dtype follows `probe`
//            (0 => our own bf16 scratch).
// K constraint: kchunk (MODE 0) / Ktot (others) must be a multiple of 128.
// ---------------------------------------------------------------------------
template<int MODE>
__global__ __launch_bounds__(256) void gemm_k(
    const void* __restrict__ Ap, int lda,
    const void* __restrict__ Bp, int ldb,
    void* __restrict__ Cp, int N, int Ktot, int kchunk,
    const u16* __restrict__ bias,
    const float* __restrict__ gnst,
    const u16* __restrict__ gng, const u16* __restrict__ gnb,
    const u16* __restrict__ fres,
    const u32* __restrict__ probe, int araw, int braw)
{
  __shared__ __align__(16) u16 As0[64*72];  // pitch 72 (144B, 16B-aligned rows)
  __shared__ __align__(16) u16 Bs0[64*72];
  __shared__ __align__(16) u16 As1[64*72];
  __shared__ __align__(16) u16 Bs1[64*72];

  const bool pf32 = probe_f32(probe);
  const bool a32 = araw && pf32, b32 = braw && pf32;

  const int tid = threadIdx.x;
  const int lane = tid & 63, wv = tid >> 6;
  const int mw = wv >> 1, nw = wv & 1;
  const int m0 = blockIdx.x * 64, n0 = blockIdx.y * 64;
  int k0 = 0, kend = Ktot;
  if (MODE == 0) { k0 = blockIdx.z * kchunk; kend = k0 + kchunk; }

  floatx4 zf = {0.f,0.f,0.f,0.f};
  floatx4 acc[2][2];
  acc[0][0]=zf; acc[0][1]=zf; acc[1][0]=zf; acc[1][1]=zf;

  const int ml = lane & 15, q = lane >> 4;
  const int ar0 = (mw*32 + ml)*72 + q*8;
  const int ar1 = ar0 + 16*72;
  const int br0 = (nw*32 + ml)*72 + q*8;
  const int br1 = br0 + 16*72;

  const int row0 = tid >> 3, colc = tid & 7;   // each thread stages rows {row0, row0+32}

  // Issue the raw global loads for k-step kk into register buffers.
  auto ld_tiles = [&](uint4 (&pa)[2][2], uint4 (&pb)[2][2], int kk){
    #pragma unroll
    for (int i=0;i<2;i++){
      int row = row0 + i*32;
      if (a32){
        const float* s = (const float*)Ap + (size_t)(m0+row)*lda + kk + colc*8;
        pa[i][0] = ((const uint4*)s)[0];
        pa[i][1] = ((const uint4*)s)[1];
      } else {
        const u16* s = (const u16*)Ap + (size_t)(m0+row)*lda + kk + colc*8;
        pa[i][0] = *(const uint4*)s;
      }
      if (b32){
        const float* s = (const float*)Bp + (size_t)(n0+row)*ldb + kk + colc*8;
        pb[i][0] = ((const uint4*)s)[0];
        pb[i][1] = ((const uint4*)s)[1];
      } else {
        const u16* s = (const u16*)Bp + (size_t)(n0+row)*ldb + kk + colc*8;
        pb[i][0] = *(const uint4*)s;
      }
    }
  };

  // Convert prefetched registers and write one LDS tile pair.
  auto stage = [&](uint4 (&pa)[2][2], uint4 (&pb)[2][2], int kk, u16* As, u16* Bs){
    #pragma unroll
    for (int i=0;i<2;i++){
      int row = row0 + i*32;
      u16* adst = &As[row*72 + colc*8];
      if (MODE == 3){
        uint4 u = pa[i][0];
        int nsamp = (m0+row) >> 8;         // 64-row tile stays within one sample
        int cbase = kk + colc*8;
        int g = cbase >> 3;                // 8 channels per group
        float mu = gnst[(nsamp*32+g)*2], rs = gnst[(nsamp*32+g)*2+1];
        float f[8] = {blo(u.x),bhi(u.x),blo(u.y),bhi(u.y),blo(u.z),bhi(u.z),blo(u.w),bhi(u.w)};
        float fn[8];
        #pragma unroll
        for (int j=0;j<8;j++){
          int c = cbase + j;
          fn[j] = (f[j]-mu)*rs*b2f(gng[c]) + b2f(gnb[c]);
        }
        uint4 t4;
        t4.x = cvtpk(fn[0],fn[1]); t4.y = cvtpk(fn[2],fn[3]);
        t4.z = cvtpk(fn[4],fn[5]); t4.w = cvtpk(fn[6],fn[7]);
        *(uint4*)adst = t4;
      } else if (a32){
        uint4 v0 = pa[i][0], v1 = pa[i][1];
        uint4 t4;
        t4.x = cvtpk(__uint_as_float(v0.x), __uint_as_float(v0.y));
        t4.y = cvtpk(__uint_as_float(v0.z), __uint_as_float(v0.w));
        t4.z = cvtpk(__uint_as_float(v1.x), __uint_as_float(v1.y));
        t4.w = cvtpk(__uint_as_float(v1.z), __uint_as_float(v1.w));
        *(uint4*)adst = t4;
      } else {
        *(uint4*)adst = pa[i][0];
      }
      u16* bdst = &Bs[row*72 + colc*8];
      if (b32){
        uint4 v0 = pb[i][0], v1 = pb[i][1];
        uint4 t4;
        t4.x = cvtpk(__uint_as_float(v0.x), __uint_as_float(v0.y));
        t4.y = cvtpk(__uint_as_float(v0.z), __uint_as_float(v0.w));
        t4.z = cvtpk(__uint_as_float(v1.x), __uint_as_float(v1.y));
        t4.w = cvtpk(__uint_as_float(v1.z), __uint_as_float(v1.w));
        *(uint4*)bdst = t4;
      } else {
        *(uint4*)bdst = pb[i][0];
      }
    }
  };

  auto mfma_step = [&](const u16* As, const u16* Bs){
    #pragma unroll
    for (int ks2=0; ks2<2; ks2++){
      int ko = ks2*32;
      short8 a0 = *(const short8*)&As[ar0 + ko];
      short8 a1 = *(const short8*)&As[ar1 + ko];
      short8 b0 = *(const short8*)&Bs[br0 + ko];
      short8 b1 = *(const short8*)&Bs[br1 + ko];
      acc[0][0] = __builtin_amdgcn_mfma_f32_16x16x32_bf16(a0, b0, acc[0][0], 0,0,0);
      acc[0][1] = __builtin_amdgcn_mfma_f32_16x16x32_bf16(a0, b1, acc[0][1], 0,0,0);
      acc[1][0] = __builtin_amdgcn_mfma_f32_16x16x32_bf16(a1, b0, acc[1][0], 0,0,0);
      acc[1][1] = __builtin_amdgcn_mfma_f32_16x16x32_bf16(a1, b1, acc[1][1], 0,0,0);
    }
  };

  // 2-deep register prefetch, refill-after-consume: a buffer's loads are
  // reissued the moment stage() drains it, giving ~2 sub-iters of latency
  // cover.  LDS ping-pong => ONE barrier per sub-iter (write[p^1] overlaps
  // read[p]; the write-after-read hazard is covered by the previous barrier).
  uint4 pa0[2][2], pb0[2][2], pa1[2][2], pb1[2][2];
  ld_tiles(pa0, pb0, k0);
  ld_tiles(pa1, pb1, k0 + 64);
  for (int kk = k0; kk < kend; kk += 128){
    // ---- sub-iter A: buf0 -> LDS0; refill buf0 with kk+128 ----
    stage(pa0, pb0, kk, As0, Bs0);
    if (kk + 128 < kend) ld_tiles(pa0, pb0, kk + 128);
    bar_lgkm();
    mfma_step(As0, Bs0);
    // ---- sub-iter B: buf1 -> LDS1; refill buf1 with kk+192 ----
    stage(pa1, pb1, kk + 64, As1, Bs1);
    if (kk + 192 < kend) ld_tiles(pa1, pb1, kk + 192);
    bar_lgkm();
    mfma_step(As1, Bs1);
  }

  // Epilogue. C/D frag mapping: col(lane&15)=n, row((lane>>4)*4+reg)=m  [m89/m91]
  const int colg = lane & 15, quad = lane >> 4;
  #pragma unroll
  for (int mi=0;mi<2;mi++){
    #pragma unroll
    for (int ni=0;ni<2;ni++){
      #pragma unroll
      for (int r=0;r<4;r++){
        int m = m0 + mw*32 + mi*16 + quad*4 + r;
        int n = n0 + nw*32 + ni*16 + colg;
        float v = acc[mi][ni][r];
        if (MODE==0){
          atomicAdd(&((float*)Cp)[(size_t)m*N + n], v);
        } else if (MODE==1){
          ((u16*)Cp)[(size_t)m*N + n] = f2b(v + b2f(bias[n]));
        } else if (MODE==3){
          ((u16*)Cp)[(size_t)m*N + n] = f2b(fmaxf(v + b2f(bias[n]), 0.f));
        } else if (MODE==4){
          int nsp = m >> 8, s = m & 255;
          ((u16*)Cp)[(size_t)m*N + n] =
              f2b(v + b2f(bias[n]) + b2f(fres[(size_t)nsp*65536 + (size_t)n*256 + s]));
        }
      }
    }
  }
}

// ---------------------------------------------------------------------------
// Fused frame-attention (softmax==1) + residual + LayerNorm(512). Block = row.
// ---------------------------------------------------------------------------
__global__ __launch_bounds__(512) void attn_ln_k(
    const float* __restrict__ tp, const u16* __restrict__ Wv, const u16* __restrict__ bv,
    const u16* __restrict__ Wo, const u16* __restrict__ bo, const u16* __restrict__ bp,
    const u16* __restrict__ g, const u16* __restrict__ bln, u16* __restrict__ enh)
{
  __shared__ float tpr[512], tpn[512], vv[512], red[16];
  int r = blockIdx.x; int n = r & 31; int rn = (n==31) ? r : r+1;
  int t = threadIdx.x;
  float bpv = b2f(bp[t]);
  tpr[t] = tp[(size_t)r*512 + t] + bpv;
  tpn[t] = tp[(size_t)rn*512 + t] + bpv;
  __syncthreads();
  {
    const uint4* w4 = (const uint4*)(Wv + (size_t)t*512);
    float acc = b2f(bv[t]);
    #pragma unroll 8
    for (int i=0;i<64;i++) acc += dot8(w4[i], &tpn[i*8]);
    vv[t] = acc;
  }
  __syncthreads();
  float x;
  {
    const uint4* w4 = (const uint4*)(Wo + (size_t)t*512);
    float acc = b2f(bo[t]);
    #pragma unroll 8
    for (int i=0;i<64;i++) acc += dot8(w4[i], &vv[i*8]);
    x = acc + tpr[t];
  }
  float s1 = wred(x), s2 = wred(x*x);
  int lane = t & 63, wid = t >> 6;
  if (lane==0){ red[wid] = s1; red[8+wid] = s2; }
  __syncthreads();
  if (t==0){
    float a=0.f, b=0.f;
    #pragma unroll
    for (int i=0;i<8;i++){ a += red[i]; b += red[8+i]; }
    float mu = a/512.f; float var = b/512.f - mu*mu;
    red[0]=mu; red[1]=rsqrtf(var+1e-5f);
  }
  __syncthreads();
  float mu = red[0], rs = red[1];
  enh[(size_t)r*512 + t] = f2b((x-mu)*rs*b2f(g[t]) + b2f(bln[t]));
}

// gap[n*256+c] = mean_s fa[n][c][s]; one wave per (n,c); fa is bf16 (n,c,s)
__global__ __launch_bounds__(256) void gap_k(const u16* __restrict__ fa, float* __restrict__ gapb){
  int wid = threadIdx.x>>6, lane = threadIdx.x&63;
  int pair = blockIdx.x*4 + wid;                   // 0..32767
  const uint2* p = (const uint2*)(fa + (size_t)pair*256);
  uint2 v = p[lane];
  float s = wred(blo(v.x)+bhi(v.x)+blo(v.y)+bhi(v.y));
  if (lane==0) gapb[pair] = s * (1.0f/256.0f);
}

// hid = relu(gap @ Wk1.T + bk1); kern = hid @ Wk2.T + bk2. One block per sample.
__global__ __launch_bounds__(256) void hidkern_k(
    const float* __restrict__ gapb, const u16* __restrict__ Wk1, const u16* __restrict__ bk1,
    const u16* __restrict__ Wk2, const u16* __restrict__ bk2, float* __restrict__ kernb)
{
  __shared__ float gl[256], hl[256];
  int nn = blockIdx.x, t = threadIdx.x;
  gl[t] = gapb[(size_t)nn*256 + t];
  __syncthreads();
  {
    const uint4* w4 = (const uint4*)(Wk1 + (size_t)t*256);
    float acc = b2f(bk1[t]);
    #pragma unroll 8
    for (int i=0;i<32;i++) acc += dot8(w4[i], &gl[i*8]);
    hl[t] = fmaxf(acc, 0.f);
  }
  __syncthreads();
  for (int qq=0; qq<9; qq++){
    int e = t*9 + qq;                              // kern flat idx = c*9 + di*3+dj
    const uint4* w4 = (const uint4*)(Wk2 + (size_t)e*256);
    float acc = b2f(bk2[e]);
    #pragma unroll 8
    for (int i=0;i<32;i++) acc += dot8(w4[i], &hl[i*8]);
    kernb[(size_t)nn*2304 + e] = acc;
  }
}

// Dynamic per-(n,c) 3x3 depthwise conv (zero pad). fa bf16 (n,c,s) -> dwb bf16 (n,s,c).
__global__ __launch_bounds__(256) void conv_k(
    const u16* __restrict__ fa, const float* __restrict__ kernb, u16* __restrict__ dwb)
{
  int b = blockIdx.x; int h = b & 15; int nn = b >> 4; int c = threadIdx.x;
  float kv[9];
  #pragma unroll
  for (int qq=0; qq<9; qq++) kv[qq] = kernb[(size_t)nn*2304 + c*9 + qq];
  float rowv[3][18];
  #pragma unroll
  for (int di=0; di<3; di++){
    int hh = h + di - 1;
    if (hh >= 0 && hh < 16){
      const u16* rp = fa + (size_t)nn*65536 + (size_t)c*256 + hh*16;
      rowv[di][0] = 0.f; rowv[di][17] = 0.f;
      #pragma unroll
      for (int w=0; w<16; w++) rowv[di][w+1] = b2f(rp[w]);
    } else {
      #pragma unroll
      for (int x=0; x<18; x++) rowv[di][x] = 0.f;
    }
  }
  #pragma unroll
  for (int w=0; w<16; w++){
    float o = 0.f;
    #pragma unroll
    for (int di=0; di<3; di++)
      o += kv[di*3]*rowv[di][w] + kv[di*3+1]*rowv[di][w+1] + kv[di*3+2]*rowv[di][w+2];
    dwb[((size_t)nn*256 + h*16 + w)*256 + c] = f2b(o);
  }
}

// GroupNorm stats per (n,g) over 8 channels x 256 spatial; out2 bf16 (n,s,c).
__global__ __launch_bounds__(256) void gnstats_k(const u16* __restrict__ out2, float* __restrict__ gnst){
  int wid = threadIdx.x>>6, lane = threadIdx.x&63;
  int grp = blockIdx.x*4 + wid; int nn = grp >> 5; int gg = grp & 31;
  const u16* base = out2 + (size_t)nn*65536 + gg*8;
  float s=0.f, ss=0.f;
  #pragma unroll 4
  for (int i=0;i<32;i++){
    int f = i*64 + lane; int sidx = f >> 3; int j = f & 7;
    float v = b2f(base[(size_t)sidx*256 + j]);
    s += v; ss += v*v;
  }
  s = wred(s); ss = wred(ss);
  if (lane==0){
    float mu = s/2048.f; float var = ss/2048.f - mu*mu;
    gnst[grp*2] = mu; gnst[grp*2+1] = rsqrtf(var + 1e-5f);
  }
}

// Final LayerNorm stats over 65536 elems per sample; z bf16.
__global__ __launch_bounds__(256) void lnstats_k(const u16* __restrict__ z, float* __restrict__ lnst){
  __shared__ float red[8];
  int nn = blockIdx.x, t = threadIdx.x;
  const uint4* p = (const uint4*)(z + (size_t)nn*65536);
  float s=0.f, ss=0.f;
  for (int i=0;i<32;i++){
    uint4 v = p[(size_t)i*256 + t];
    float f0=blo(v.x),f1=bhi(v.x),f2=blo(v.y),f3=bhi(v.y);
    float f4=blo(v.z),f5=bhi(v.z),f6=blo(v.w),f7=bhi(v.w);
    s  += (f0+f1)+(f2+f3)+(f4+f5)+(f6+f7);
    ss += (f0*f0+f1*f1)+(f2*f2+f3*f3)+(f4*f4+f5*f5)+(f6*f6+f7*f7);
  }
  s = wred(s); ss = wred(ss);
  int lane = t&63, wid = t>>6;
  if (lane==0){ red[wid]=s; red[4+wid]=ss; }
  __syncthreads();
  if (t==0){
    float a=red[0]+red[1]+red[2]+red[3];
    float b=red[4]+red[5]+red[6]+red[7];
    float mu = a/65536.f; float var = b/65536.f - mu*mu;
    lnst[nn*2] = mu; lnst[nn*2+1] = rsqrtf(var + 1e-5f);
  }
}

// Apply LN + dn scale/shift, transposing (n,s,c) -> (n,c,h,w). Output dtype adaptive.
__global__ __launch_bounds__(256) void final_k(
    const u16* __restrict__ z, const float* __restrict__ lnst,
    const u16* __restrict__ dng, const u16* __restrict__ dnb,
    void* __restrict__ outp, const u32* __restrict__ probe)
{
  __shared__ float zt[32*257];
  const bool pf32 = probe_f32(probe);
  int b = blockIdx.x; int nn = b >> 3; int s0 = (b & 7)*32;
  int t = threadIdx.x;
  {
    int srow = t >> 3; int c0 = (t & 7)*32;
    const uint4* p = (const uint4*)(z + (size_t)nn*65536 + (size_t)(s0+srow)*256 + c0);
    float* dst = &zt[srow*257 + c0];
    #pragma unroll
    for (int i=0;i<4;i++){
      uint4 v = p[i];
      dst[i*8+0]=blo(v.x); dst[i*8+1]=bhi(v.x); dst[i*8+2]=blo(v.y); dst[i*8+3]=bhi(v.y);
      dst[i*8+4]=blo(v.z); dst[i*8+5]=bhi(v.z); dst[i*8+6]=blo(v.w); dst[i*8+7]=bhi(v.w);
    }
  }
  __syncthreads();
  float mu = lnst[nn*2], rs = lnst[nn*2+1];
  int sl = t & 31, cq = t >> 5;                    // cq in [0,8)
  for (int i=0;i<32;i++){
    int c = i*8 + cq;
    float v = (zt[sl*257 + c] - mu) * rs;
    int gidx = c*256 + s0 + sl;
    float res = v*b2f(dng[gidx]) + b2f(dnb[gidx]);
    size_t oi = (size_t)nn*65536 + gidx;
    if (pf32) ((float*)outp)[oi] = res;
    else      ((u16*)outp)[oi]   = f2b(res);
  }
}

// ---------------------------------------------------------------------------
extern "C" void kernel_launch(void* const* d_in, const int* in_sizes, int n_in,
                              void* d_out, int out_size, void* d_ws, size_t ws_size,
                              hipStream_t stream) {
  (void)in_sizes; (void)n_in; (void)out_size; (void)ws_size;
  const u32* probe = (const u32*)d_in[21];   // gn_g == ones

  // Canonical bf16 copies of small inputs (cvt region offsets, elems):
  char* w = (char*)d_ws;
  u16* cvt = (u16*)w;
  u16 *cWv  = cvt+0,       *cWo  = cvt+262144, *cWk1 = cvt+524288, *cWk2 = cvt+589824;
  u16 *cWpc = cvt+1179648, *cWf1 = cvt+1245184,*cWf2 = cvt+1310720;
  u16 *cdng = cvt+1376256, *cdnb = cvt+1441792,*cbu  = cvt+1507328;
  u16 *cbp  = cvt+1572864, *cbv  = cvt+1573376,*cbo  = cvt+1573888;
  u16 *cln1g= cvt+1574400, *cln1b= cvt+1574912,*cbk1 = cvt+1575424,*cbk2 = cvt+1575680;
  u16 *cbpc = cvt+1577984, *cgng = cvt+1578240,*cgnb = cvt+1578496;
  u16 *cbf1 = cvt+1578752, *cbf2 = cvt+1579008;

  float* tp_raw = (float*)(w + 4194304);   // 128x512 f32
  u16*   enh    = (u16*)  (w + 4456448);   // 128x512 bf16
  float* gapb   = (float*)(w + 4587520);   // 128x256 f32
  float* kernb  = (float*)(w + 4718592);   // 128x2304 f32
  float* gnst   = (float*)(w + 5898240);   // 128x32x2 f32
  float* lnst   = (float*)(w + 5931008);   // 128x2 f32
  u16*   fa     = (u16*)  (w + 8388608);   // 128x256x256 bf16 (n,c,s) 16MB
  u16*   out2   = (u16*)  (w + 25165824);  // 128x256x256 bf16 (n,s,c) 16MB
  u16*   z      = out2;                    // reuse after PW2 consumes out2
  u16*   dwb    = (u16*)d_out;             // d_out as scratch (dead until final_k)
  u16*   y1     = dwb;

  SrcTab st;
  st.p[0]=d_in[9];  st.p[1]=d_in[11]; st.p[2]=d_in[15]; st.p[3]=d_in[17];
  st.p[4]=d_in[19]; st.p[5]=d_in[23]; st.p[6]=d_in[25]; st.p[7]=d_in[27];
  st.p[8]=d_in[28]; st.p[9]=d_in[4];  st.p[10]=d_in[2]; st.p[11]=d_in[10];
  st.p[12]=d_in[12];st.p[13]=d_in[13];st.p[14]=d_in[14];st.p[15]=d_in[16];
  st.p[16]=d_in[18];st.p[17]=d_in[20];st.p[18]=d_in[21];st.p[19]=d_in[22];
  st.p[20]=d_in[24];st.p[21]=d_in[26];

  // 0) convert small inputs
  cvt_k<<<dim3(576,22), 256, 0, stream>>>(st, probe, cvt);
  // 1) tp = tokens @ Wp.T  (split-K, atomic f32; bias bp added in attn)
  // kchunk=512 / z=128 -> 2048 blocks; register-pipelined staging loop.
  hipMemsetAsync(tp_raw, 0, 128*512*4, stream);
  gemm_k<0><<<dim3(2,8,128), 256, 0, stream>>>(d_in[0], 65536, d_in[1], 65536, tp_raw,
      512, 65536, 512, nullptr, nullptr, nullptr, nullptr, nullptr, probe, 1, 1);
  // 2) attention + residual + LN -> enh
  attn_ln_k<<<128, 512, 0, stream>>>(tp_raw, cWv, cbv, cWo, cbo, cbp, cln1g, cln1b, enh);
  // 3) feat_attn = enh @ Wu.T + bu -> fa bf16 (n,c,s)
  gemm_k<1><<<dim3(2,1024,1), 256, 0, stream>>>(enh, 512, d_in[3], 512, fa,
      65536, 512, 0, cbu, nullptr, nullptr, nullptr, nullptr, probe, 0, 1);
  // 4) gap
  gap_k<<<8192, 256, 0, stream>>>(fa, gapb);
  // 5) hid/kern
  hidkern_k<<<128, 256, 0, stream>>>(gapb, cWk1, cbk1, cWk2, cbk2, kernb);
  // 6) dynamic depthwise 3x3 -> dwb bf16 (n,s,c) in d_out
  conv_k<<<2048, 256, 0, stream>>>(fa, kernb, dwb);
  // 7) out2 = dw @ Wpc.T + bpc
  gemm_k<1><<<dim3(512,4,1), 256, 0, stream>>>(dwb, 256, cWpc, 256, out2,
      256, 256, 0, cbpc, nullptr, nullptr, nullptr, nullptr, probe, 0, 0);
  // 8) GroupNorm stats
  gnstats_k<<<1024, 256, 0, stream>>>(out2, gnst);
  // 9) y1 = relu(GN(out2) @ Wf1.T + bf1)  (GN fused into A staging; y1 in d_out)
  gemm_k<3><<<dim3(512,4,1), 256, 0, stream>>>(out2, 256, cWf1, 256, y1,
      256, 256, 0, cbf1, gnst, cgng, cgnb, nullptr, probe, 0, 0);
  // 10) z = y1 @ Wf2.T + bf2 + feat_attn  (z overlays out2)
  gemm_k<4><<<dim3(512,4,1), 256, 0, stream>>>(y1, 256, cWf2, 256, z,
      256, 256, 0, cbf2, nullptr, nullptr, nullptr, fa, probe, 0, 0);
  // 11) final LN stats
  lnstats_k<<<128, 256, 0, stream>>>(z, lnst);
  // 12) LN * dn_g + dn_b, transpose to (n,c,h,w), adaptive out dtype
  final_k<<<1024, 256, 0, stream>>>(z, lnst, cdng, cdnb, d_out, probe);
}

// Round 5
// 615.669 us; speedup vs baseline: 1.0245x; 1.0245x over previous
//
#include <hip/hip_runtime.h>

// Problem: B=4, N_FRAMES=32 -> BN=128 samples; C=256, S=16 -> 256 spatial;
// TOKEN=65536; D=512.  softmax over size-1 axis == 1 => Wq/bq/Wk/bk are dead.
//
// Runtime dtype adaptivity: probe = gn_g (all ones).
//   f32 buffer:  first u32 == 0x3F800000
//   bf16 buffer: first u32 == 0x3F803F80
// All kernels branch (wave-uniform) on this; output dtype follows the same flag.

typedef unsigned short u16;
typedef unsigned int u32;
typedef __attribute__((ext_vector_type(8))) short short8;   // 8 bf16 (4 VGPRs)
typedef __attribute__((ext_vector_type(4))) float floatx4;  // MFMA C/D frag

__device__ __forceinline__ float b2f(u16 h){ return __uint_as_float(((u32)h)<<16); }
__device__ __forceinline__ u16 f2b(float f){
  u32 u = __float_as_uint(f);
  u = (u + 0x7FFFu + ((u>>16)&1u)) >> 16;   // RNE
  return (u16)u;
}
// Packed RNE f32x2 -> bf16x2 (dst.lo = bf16(lo), dst.hi = bf16(hi)).
__device__ __forceinline__ u32 cvtpk(float lo, float hi){
  u32 r;
  asm("v_cvt_pk_bf16_f32 %0, %1, %2" : "=v"(r) : "v"(lo), "v"(hi));
  return r;
}
__device__ __forceinline__ float blo(u32 w){ return __uint_as_float(w<<16); }
__device__ __forceinline__ float bhi(u32 w){ return __uint_as_float(w & 0xFFFF0000u); }
__device__ __forceinline__ bool probe_f32(const u32* p){ return p[0]==0x3F800000u; }

// Async global->LDS, 16B per lane. LDS dest must be WAVE-UNIFORM base;
// HW writes base + lane*16. Global source address is per-lane.
__device__ __forceinline__ void gload_lds16(const void* g, void* l){
  __builtin_amdgcn_global_load_lds(
      (const __attribute__((address_space(1))) unsigned int*)g,
      (__attribute__((address_space(3))) unsigned int*)l, 16, 0, 0);
}

__device__ __forceinline__ float wred(float v){
  #pragma unroll
  for (int o=32;o>0;o>>=1) v += __shfl_down(v, o, 64);
  return v;
}

__device__ __forceinline__ float dot8(uint4 u, const float* t){
  return t[0]*blo(u.x)+t[1]*bhi(u.x)+t[2]*blo(u.y)+t[3]*bhi(u.y)
       + t[4]*blo(u.z)+t[5]*bhi(u.z)+t[6]*blo(u.w)+t[7]*bhi(u.w);
}

// Raw s_barrier WITHOUT the compiler's vmcnt(0) drain (for the reg-pipelined
// gemm_k). ds_write visibility needs lgkmcnt(0) only.
__device__ __forceinline__ void bar_lgkm(){
  asm volatile("s_waitcnt lgkmcnt(0)" ::: "memory");
  __builtin_amdgcn_sched_barrier(0);
  __builtin_amdgcn_s_barrier();
  asm volatile("" ::: "memory");
}
__device__ __forceinline__ void bar(){
  asm volatile("" ::: "memory");
  __builtin_amdgcn_s_barrier();
  asm volatile("" ::: "memory");
}

// ---------------------------------------------------------------------------
// Convert the 22 small input tensors to a canonical bf16 region in ws.
// ---------------------------------------------------------------------------
struct SrcTab { const void* p[22]; };

__global__ __launch_bounds__(256) void cvt_k(SrcTab st, const u32* probe, u16* dst){
  constexpr int ns[22]   = {262144,262144,65536,589824,65536,65536,65536,65536,65536,
                            65536,512,512,512,512,512,256,2304,256,256,256,256,256};
  constexpr int offs[22] = {0,262144,524288,589824,1179648,1245184,1310720,1376256,1441792,
                            1507328,1572864,1573376,1573888,1574400,1574912,1575424,1575680,
                            1577984,1578240,1578496,1578752,1579008};
  int t = blockIdx.y;
  int e = (blockIdx.x*256 + threadIdx.x)*4;
  if (e >= ns[t]) return;
  u16* d = dst + offs[t] + e;
  if (probe_f32(probe)){
    float4 v = *(const float4*)((const float*)st.p[t] + e);
    d[0]=f2b(v.x); d[1]=f2b(v.y); d[2]=f2b(v.z); d[3]=f2b(v.w);
  } else {
    *(uint2*)d = *(const uint2*)((const u16*)st.p[t] + e);
  }
}

// ---------------------------------------------------------------------------
// Split-K GEMM for step 1 (tp = tokens @ Wp.T), raw operands, atomic f32 out.
// global_load_lds width=16 staging of RAW tiles (f32 or bf16 per probe),
// BK=32, LDS double-buffer, plain __syncthreads (m97 structure).
// Conversion f32->bf16 happens at LDS->VGPR fragment read (cvt_pk).
// Bank-conflict fix: linear LDS dest (required by gload_lds) + involutive
// XOR swizzle applied to the per-lane GLOBAL source AND the LDS read:
//   f32 : row = 32 f32 = 8 chunks;  slot = c ^ (row & 7)       -> 2 lanes/bank
//   bf16: row = 32 bf16 = 4 chunks; slot = c ^ ((row>>1) & 3)  -> 2 lanes/bank
// kchunk must be a multiple of 64.
// ---------------------------------------------------------------------------
__global__ __launch_bounds__(256) void gemm32_k(
    const void* __restrict__ Ap, int lda,
    const void* __restrict__ Bp, int ldb,
    float* __restrict__ Cp, int N, int kchunk,
    const u32* __restrict__ probe)
{
  __shared__ __align__(16) char As0[8192];  // 64 rows x 32 f32 (128B) linear
  __shared__ __align__(16) char Bs0[8192];
  __shared__ __align__(16) char As1[8192];
  __shared__ __align__(16) char Bs1[8192];

  const bool pf32 = probe_f32(probe);
  const int tid = threadIdx.x;
  const int lane = tid & 63, wv = tid >> 6;
  const int mw = wv >> 1, nw = wv & 1;
  const int m0 = blockIdx.x * 64, n0 = blockIdx.y * 64;
  const int k0 = blockIdx.z * kchunk, kend = k0 + kchunk;

  floatx4 zf = {0.f,0.f,0.f,0.f};
  floatx4 acc[2][2];
  acc[0][0]=zf; acc[0][1]=zf; acc[1][0]=zf; acc[1][1]=zf;

  const int ml = lane & 15, q = lane >> 4;

  // ---------------- f32 path ----------------
  auto stage32 = [&](char* As, char* Bs, int kk){
    #pragma unroll
    for (int i=0;i<2;i++){
      int g = wv*2 + i;                 // wave-uniform group 0..7
      int ci = g*64 + lane;             // linear LDS chunk (16B units)
      int row = ci >> 3, slot = ci & 7;
      int c = slot ^ (row & 7);         // source chunk (involution)
      gload_lds16((const float*)Ap + (size_t)(m0+row)*lda + kk + c*4, As + g*1024);
      gload_lds16((const float*)Bp + (size_t)(n0+row)*ldb + kk + c*4, Bs + g*1024);
    }
  };
  auto compute32 = [&](const char* As, const char* Bs){
    short8 af[2], bf2[2];
    #pragma unroll
    for (int i=0;i<2;i++){
      int arow = mw*32 + ml + i*16;
      int r7 = arow & 7;
      uint4 u0 = *(const uint4*)(As + arow*128 + ((q*2)   ^ r7)*16);
      uint4 u1 = *(const uint4*)(As + arow*128 + ((q*2+1) ^ r7)*16);
      uint4 t;
      t.x = cvtpk(__uint_as_float(u0.x), __uint_as_float(u0.y));
      t.y = cvtpk(__uint_as_float(u0.z), __uint_as_float(u0.w));
      t.z = cvtpk(__uint_as_float(u1.x), __uint_as_float(u1.y));
      t.w = cvtpk(__uint_as_float(u1.z), __uint_as_float(u1.w));
      union { uint4 u; short8 s; } ca; ca.u = t; af[i] = ca.s;
      int brow = nw*32 + ml + i*16;
      int s7 = brow & 7;
      uint4 v0 = *(const uint4*)(Bs + brow*128 + ((q*2)   ^ s7)*16);
      uint4 v1 = *(const uint4*)(Bs + brow*128 + ((q*2+1) ^ s7)*16);
      uint4 w4;
      w4.x = cvtpk(__uint_as_float(v0.x), __uint_as_float(v0.y));
      w4.y = cvtpk(__uint_as_float(v0.z), __uint_as_float(v0.w));
      w4.z = cvtpk(__uint_as_float(v1.x), __uint_as_float(v1.y));
      w4.w = cvtpk(__uint_as_float(v1.z), __uint_as_float(v1.w));
      union { uint4 u; short8 s; } cb; cb.u = w4; bf2[i] = cb.s;
    }
    acc[0][0] = __builtin_amdgcn_mfma_f32_16x16x32_bf16(af[0], bf2[0], acc[0][0], 0,0,0);
    acc[0][1] = __builtin_amdgcn_mfma_f32_16x16x32_bf16(af[0], bf2[1], acc[0][1], 0,0,0);
    acc[1][0] = __builtin_amdgcn_mfma_f32_16x16x32_bf16(af[1], bf2[0], acc[1][0], 0,0,0);
    acc[1][1] = __builtin_amdgcn_mfma_f32_16x16x32_bf16(af[1], bf2[1], acc[1][1], 0,0,0);
  };

  // ---------------- bf16 path ----------------
  auto stage16 = [&](char* As, char* Bs, int kk){
    int ci = wv*64 + lane;              // 0..255 chunks (4KB tile)
    int row = ci >> 2, slot = ci & 3;
    int c = slot ^ ((row>>1) & 3);
    gload_lds16((const u16*)Ap + (size_t)(m0+row)*lda + kk + c*8, As + wv*1024);
    gload_lds16((const u16*)Bp + (size_t)(n0+row)*ldb + kk + c*8, Bs + wv*1024);
  };
  auto compute16 = [&](const char* As, const char* Bs){
    short8 af[2], bf2[2];
    #pragma unroll
    for (int i=0;i<2;i++){
      int arow = mw*32 + ml + i*16;
      int sa = q ^ ((arow>>1) & 3);
      union { uint4 u; short8 s; } ca; ca.u = *(const uint4*)(As + arow*64 + sa*16);
      af[i] = ca.s;
      int brow = nw*32 + ml + i*16;
      int sb = q ^ ((brow>>1) & 3);
      union { uint4 u; short8 s; } cb; cb.u = *(const uint4*)(Bs + brow*64 + sb*16);
      bf2[i] = cb.s;
    }
    acc[0][0] = __builtin_amdgcn_mfma_f32_16x16x32_bf16(af[0], bf2[0], acc[0][0], 0,0,0);
    acc[0][1] = __builtin_amdgcn_mfma_f32_16x16x32_bf16(af[0], bf2[1], acc[0][1], 0,0,0);
    acc[1][0] = __builtin_amdgcn_mfma_f32_16x16x32_bf16(af[1], bf2[0], acc[1][0], 0,0,0);
    acc[1][1] = __builtin_amdgcn_mfma_f32_16x16x32_bf16(af[1], bf2[1], acc[1][1], 0,0,0);
  };

  if (pf32){
    stage32(As0, Bs0, k0);
    __syncthreads();
    for (int kk = k0; kk < kend; kk += 64){
      stage32(As1, Bs1, kk + 32);   // async; in flight during compute
      compute32(As0, Bs0);
      __syncthreads();              // drains vmcnt -> buf1 ready
      if (kk + 64 < kend) stage32(As0, Bs0, kk + 64);
      compute32(As1, Bs1);
      __syncthreads();
    }
  } else {
    stage16(As0, Bs0, k0);
    __syncthreads();
    for (int kk = k0; kk < kend; kk += 64){
      stage16(As1, Bs1, kk + 32);
      compute16(As0, Bs0);
      __syncthreads();
      if (kk + 64 < kend) stage16(As0, Bs0, kk + 64);
      compute16(As1, Bs1);
      __syncthreads();
    }
  }

  // Epilogue. C/D frag mapping: col(lane&15)=n, row((lane>>4)*4+reg)=m  [m89/m91]
  const int colg = lane & 15, quad = lane >> 4;
  #pragma unroll
  for (int mi=0;mi<2;mi++){
    #pragma unroll
    for (int ni=0;ni<2;ni++){
      #pragma unroll
      for (int r=0;r<4;r++){
        int m = m0 + mw*32 + mi*16 + quad*4 + r;
        int n = n0 + nw*32 + ni*16 + colg;
        atomicAdd(&Cp[(size_t)m*N + n], acc[mi][ni][r]);
      }
    }
  }
}

// ---------------------------------------------------------------------------
// 64x64-tile MFMA GEMM (NT): C[m][n] = sum_k A[m][k]*B[n][k] (+epilogue)
// R3 structure: register double-buffered global loads, raw s_barrier
// (no vmcnt drain) so prefetched loads stay in flight across barriers.
// MODE 1: C_bf16 = acc + bias[n]
// MODE 3: A = bf16 with fused GroupNorm-normalize at staging; C_bf16 = relu(acc+bias)
// MODE 4: C_bf16 = acc + bias[n] + fres (bf16 residual, (n,c,s) layout)
// araw/braw: operand is a RAW input buffer whose dtype follows `probe`
//            (0 => our own bf16 scratch).
// K constraint: Ktot must be a multiple of 128.
// ---------------------------------------------------------------------------
template<int MODE>
__global__ __launch_bounds__(256) void gemm_k(
    const void* __restrict__ Ap, int lda,
    const void* __restrict__ Bp, int ldb,
    void* __restrict__ Cp, int N, int Ktot, int kchunk,
    const u16* __restrict__ bias,
    const float* __restrict__ gnst,
    const u16* __restrict__ gng, const u16* __restrict__ gnb,
    const u16* __restrict__ fres,
    const u32* __restrict__ probe, int araw, int braw)
{
  __shared__ __align__(16) u16 As[64*72];  // pitch 72 (144B, 16B-aligned rows)
  __shared__ __align__(16) u16 Bs[64*72];

  const bool pf32 = probe_f32(probe);
  const bool a32 = araw && pf32, b32 = braw && pf32;

  const int tid = threadIdx.x;
  const int lane = tid & 63, wv = tid >> 6;
  const int mw = wv >> 1, nw = wv & 1;
  const int m0 = blockIdx.x * 64, n0 = blockIdx.y * 64;
  int k0 = 0, kend = Ktot;
  (void)kchunk;

  floatx4 zf = {0.f,0.f,0.f,0.f};
  floatx4 acc[2][2];
  acc[0][0]=zf; acc[0][1]=zf; acc[1][0]=zf; acc[1][1]=zf;

  const int ml = lane & 15, q = lane >> 4;
  const int ar0 = (mw*32 + ml)*72 + q*8;
  const int ar1 = ar0 + 16*72;
  const int br0 = (nw*32 + ml)*72 + q*8;
  const int br1 = br0 + 16*72;

  const int row0 = tid >> 3, colc = tid & 7;   // each thread stages rows {row0, row0+32}

  // Issue the raw global loads for k-step kk into register buffers.
  auto ld_tiles = [&](uint4 (&pa)[2][2], uint4 (&pb)[2][2], int kk){
    #pragma unroll
    for (int i=0;i<2;i++){
      int row = row0 + i*32;
      if (a32){
        const float* s = (const float*)Ap + (size_t)(m0+row)*lda + kk + colc*8;
        pa[i][0] = ((const uint4*)s)[0];
        pa[i][1] = ((const uint4*)s)[1];
      } else {
        const u16* s = (const u16*)Ap + (size_t)(m0+row)*lda + kk + colc*8;
        pa[i][0] = *(const uint4*)s;
      }
      if (b32){
        const float* s = (const float*)Bp + (size_t)(n0+row)*ldb + kk + colc*8;
        pb[i][0] = ((const uint4*)s)[0];
        pb[i][1] = ((const uint4*)s)[1];
      } else {
        const u16* s = (const u16*)Bp + (size_t)(n0+row)*ldb + kk + colc*8;
        pb[i][0] = *(const uint4*)s;
      }
    }
  };

  // Convert prefetched registers and write the LDS tiles.
  auto stage = [&](uint4 (&pa)[2][2], uint4 (&pb)[2][2], int kk){
    #pragma unroll
    for (int i=0;i<2;i++){
      int row = row0 + i*32;
      u16* adst = &As[row*72 + colc*8];
      if (MODE == 3){
        uint4 u = pa[i][0];
        int nsamp = (m0+row) >> 8;         // 64-row tile stays within one sample
        int cbase = kk + colc*8;
        int g = cbase >> 3;                // 8 channels per group
        float mu = gnst[(nsamp*32+g)*2], rs = gnst[(nsamp*32+g)*2+1];
        float f[8] = {blo(u.x),bhi(u.x),blo(u.y),bhi(u.y),blo(u.z),bhi(u.z),blo(u.w),bhi(u.w)};
        float fn[8];
        #pragma unroll
        for (int j=0;j<8;j++){
          int c = cbase + j;
          fn[j] = (f[j]-mu)*rs*b2f(gng[c]) + b2f(gnb[c]);
        }
        uint4 t4;
        t4.x = cvtpk(fn[0],fn[1]); t4.y = cvtpk(fn[2],fn[3]);
        t4.z = cvtpk(fn[4],fn[5]); t4.w = cvtpk(fn[6],fn[7]);
        *(uint4*)adst = t4;
      } else if (a32){
        uint4 v0 = pa[i][0], v1 = pa[i][1];
        uint4 t4;
        t4.x = cvtpk(__uint_as_float(v0.x), __uint_as_float(v0.y));
        t4.y = cvtpk(__uint_as_float(v0.z), __uint_as_float(v0.w));
        t4.z = cvtpk(__uint_as_float(v1.x), __uint_as_float(v1.y));
        t4.w = cvtpk(__uint_as_float(v1.z), __uint_as_float(v1.w));
        *(uint4*)adst = t4;
      } else {
        *(uint4*)adst = pa[i][0];
      }
      u16* bdst = &Bs[row*72 + colc*8];
      if (b32){
        uint4 v0 = pb[i][0], v1 = pb[i][1];
        uint4 t4;
        t4.x = cvtpk(__uint_as_float(v0.x), __uint_as_float(v0.y));
        t4.y = cvtpk(__uint_as_float(v0.z), __uint_as_float(v0.w));
        t4.z = cvtpk(__uint_as_float(v1.x), __uint_as_float(v1.y));
        t4.w = cvtpk(__uint_as_float(v1.z), __uint_as_float(v1.w));
        *(uint4*)bdst = t4;
      } else {
        *(uint4*)bdst = pb[i][0];
      }
    }
  };

  auto mfma_step = [&](){
    #pragma unroll
    for (int ks2=0; ks2<2; ks2++){
      int ko = ks2*32;
      short8 a0 = *(const short8*)&As[ar0 + ko];
      short8 a1 = *(const short8*)&As[ar1 + ko];
      short8 b0 = *(const short8*)&Bs[br0 + ko];
      short8 b1 = *(const short8*)&Bs[br1 + ko];
      acc[0][0] = __builtin_amdgcn_mfma_f32_16x16x32_bf16(a0, b0, acc[0][0], 0,0,0);
      acc[0][1] = __builtin_amdgcn_mfma_f32_16x16x32_bf16(a0, b1, acc[0][1], 0,0,0);
      acc[1][0] = __builtin_amdgcn_mfma_f32_16x16x32_bf16(a1, b0, acc[1][0], 0,0,0);
      acc[1][1] = __builtin_amdgcn_mfma_f32_16x16x32_bf16(a1, b1, acc[1][1], 0,0,0);
    }
  };

  // Ping-pong register buffers, unroll x2 (static indexing only).
  uint4 pa0[2][2], pb0[2][2], pa1[2][2], pb1[2][2];
  ld_tiles(pa0, pb0, k0);
  for (int kk = k0; kk < kend; kk += 128){
    bar();                                  // prev MFMA readers done with LDS
    ld_tiles(pa1, pb1, kk + 64);            // in flight during stage+MFMA
    stage(pa0, pb0, kk);
    bar_lgkm();                             // ds_writes visible; vmcnt NOT drained
    mfma_step();
    bar();
    if (kk + 128 < kend) ld_tiles(pa0, pb0, kk + 128);
    stage(pa1, pb1, kk + 64);
    bar_lgkm();
    mfma_step();
  }

  // Epilogue. C/D frag mapping: col(lane&15)=n, row((lane>>4)*4+reg)=m  [m89/m91]
  const int colg = lane & 15, quad = lane >> 4;
  #pragma unroll
  for (int mi=0;mi<2;mi++){
    #pragma unroll
    for (int ni=0;ni<2;ni++){
      #pragma unroll
      for (int r=0;r<4;r++){
        int m = m0 + mw*32 + mi*16 + quad*4 + r;
        int n = n0 + nw*32 + ni*16 + colg;
        float v = acc[mi][ni][r];
        if (MODE==1){
          ((u16*)Cp)[(size_t)m*N + n] = f2b(v + b2f(bias[n]));
        } else if (MODE==3){
          ((u16*)Cp)[(size_t)m*N + n] = f2b(fmaxf(v + b2f(bias[n]), 0.f));
        } else if (MODE==4){
          int nsp = m >> 8, s = m & 255;
          ((u16*)Cp)[(size_t)m*N + n] =
              f2b(v + b2f(bias[n]) + b2f(fres[(size_t)nsp*65536 + (size_t)n*256 + s]));
        }
      }
    }
  }
}

// ---------------------------------------------------------------------------
// Fused frame-attention (softmax==1) + residual + LayerNorm(512). Block = row.
// ---------------------------------------------------------------------------
__global__ __launch_bounds__(512) void attn_ln_k(
    const float* __restrict__ tp, const u16* __restrict__ Wv, const u16* __restrict__ bv,
    const u16* __restrict__ Wo, const u16* __restrict__ bo, const u16* __restrict__ bp,
    const u16* __restrict__ g, const u16* __restrict__ bln, u16* __restrict__ enh)
{
  __shared__ float tpr[512], tpn[512], vv[512], red[16];
  int r = blockIdx.x; int n = r & 31; int rn = (n==31) ? r : r+1;
  int t = threadIdx.x;
  float bpv = b2f(bp[t]);
  tpr[t] = tp[(size_t)r*512 + t] + bpv;
  tpn[t] = tp[(size_t)rn*512 + t] + bpv;
  __syncthreads();
  {
    const uint4* w4 = (const uint4*)(Wv + (size_t)t*512);
    float acc = b2f(bv[t]);
    #pragma unroll 8
    for (int i=0;i<64;i++) acc += dot8(w4[i], &tpn[i*8]);
    vv[t] = acc;
  }
  __syncthreads();
  float x;
  {
    const uint4* w4 = (const uint4*)(Wo + (size_t)t*512);
    float acc = b2f(bo[t]);
    #pragma unroll 8
    for (int i=0;i<64;i++) acc += dot8(w4[i], &vv[i*8]);
    x = acc + tpr[t];
  }
  float s1 = wred(x), s2 = wred(x*x);
  int lane = t & 63, wid = t >> 6;
  if (lane==0){ red[wid] = s1; red[8+wid] = s2; }
  __syncthreads();
  if (t==0){
    float a=0.f, b=0.f;
    #pragma unroll
    for (int i=0;i<8;i++){ a += red[i]; b += red[8+i]; }
    float mu = a/512.f; float var = b/512.f - mu*mu;
    red[0]=mu; red[1]=rsqrtf(var+1e-5f);
  }
  __syncthreads();
  float mu = red[0], rs = red[1];
  enh[(size_t)r*512 + t] = f2b((x-mu)*rs*b2f(g[t]) + b2f(bln[t]));
}

// gap[n*256+c] = mean_s fa[n][c][s]; one wave per (n,c); fa is bf16 (n,c,s)
__global__ __launch_bounds__(256) void gap_k(const u16* __restrict__ fa, float* __restrict__ gapb){
  int wid = threadIdx.x>>6, lane = threadIdx.x&63;
  int pair = blockIdx.x*4 + wid;                   // 0..32767
  const uint2* p = (const uint2*)(fa + (size_t)pair*256);
  uint2 v = p[lane];
  float s = wred(blo(v.x)+bhi(v.x)+blo(v.y)+bhi(v.y));
  if (lane==0) gapb[pair] = s * (1.0f/256.0f);
}

// hid = relu(gap @ Wk1.T + bk1); kern = hid @ Wk2.T + bk2. One block per sample.
__global__ __launch_bounds__(256) void hidkern_k(
    const float* __restrict__ gapb, const u16* __restrict__ Wk1, const u16* __restrict__ bk1,
    const u16* __restrict__ Wk2, const u16* __restrict__ bk2, float* __restrict__ kernb)
{
  __shared__ float gl[256], hl[256];
  int nn = blockIdx.x, t = threadIdx.x;
  gl[t] = gapb[(size_t)nn*256 + t];
  __syncthreads();
  {
    const uint4* w4 = (const uint4*)(Wk1 + (size_t)t*256);
    float acc = b2f(bk1[t]);
    #pragma unroll 8
    for (int i=0;i<32;i++) acc += dot8(w4[i], &gl[i*8]);
    hl[t] = fmaxf(acc, 0.f);
  }
  __syncthreads();
  for (int qq=0; qq<9; qq++){
    int e = t*9 + qq;                              // kern flat idx = c*9 + di*3+dj
    const uint4* w4 = (const uint4*)(Wk2 + (size_t)e*256);
    float acc = b2f(bk2[e]);
    #pragma unroll 8
    for (int i=0;i<32;i++) acc += dot8(w4[i], &hl[i*8]);
    kernb[(size_t)nn*2304 + e] = acc;
  }
}

// Dynamic per-(n,c) 3x3 depthwise conv (zero pad). fa bf16 (n,c,s) -> dwb bf16 (n,s,c).
__global__ __launch_bounds__(256) void conv_k(
    const u16* __restrict__ fa, const float* __restrict__ kernb, u16* __restrict__ dwb)
{
  int b = blockIdx.x; int h = b & 15; int nn = b >> 4; int c = threadIdx.x;
  float kv[9];
  #pragma unroll
  for (int qq=0; qq<9; qq++) kv[qq] = kernb[(size_t)nn*2304 + c*9 + qq];
  float rowv[3][18];
  #pragma unroll
  for (int di=0; di<3; di++){
    int hh = h + di - 1;
    if (hh >= 0 && hh < 16){
      const u16* rp = fa + (size_t)nn*65536 + (size_t)c*256 + hh*16;
      rowv[di][0] = 0.f; rowv[di][17] = 0.f;
      #pragma unroll
      for (int w=0; w<16; w++) rowv[di][w+1] = b2f(rp[w]);
    } else {
      #pragma unroll
      for (int x=0; x<18; x++) rowv[di][x] = 0.f;
    }
  }
  #pragma unroll
  for (int w=0; w<16; w++){
    float o = 0.f;
    #pragma unroll
    for (int di=0; di<3; di++)
      o += kv[di*3]*rowv[di][w] + kv[di*3+1]*rowv[di][w+1] + kv[di*3+2]*rowv[di][w+2];
    dwb[((size_t)nn*256 + h*16 + w)*256 + c] = f2b(o);
  }
}

// GroupNorm stats per (n,g) over 8 channels x 256 spatial; out2 bf16 (n,s,c).
__global__ __launch_bounds__(256) void gnstats_k(const u16* __restrict__ out2, float* __restrict__ gnst){
  int wid = threadIdx.x>>6, lane = threadIdx.x&63;
  int grp = blockIdx.x*4 + wid; int nn = grp >> 5; int gg = grp & 31;
  const u16* base = out2 + (size_t)nn*65536 + gg*8;
  float s=0.f, ss=0.f;
  #pragma unroll 4
  for (int i=0;i<32;i++){
    int f = i*64 + lane; int sidx = f >> 3; int j = f & 7;
    float v = b2f(base[(size_t)sidx*256 + j]);
    s += v; ss += v*v;
  }
  s = wred(s); ss = wred(ss);
  if (lane==0){
    float mu = s/2048.f; float var = ss/2048.f - mu*mu;
    gnst[grp*2] = mu; gnst[grp*2+1] = rsqrtf(var + 1e-5f);
  }
}

// Final LayerNorm stats over 65536 elems per sample; z bf16.
__global__ __launch_bounds__(256) void lnstats_k(const u16* __restrict__ z, float* __restrict__ lnst){
  __shared__ float red[8];
  int nn = blockIdx.x, t = threadIdx.x;
  const uint4* p = (const uint4*)(z + (size_t)nn*65536);
  float s=0.f, ss=0.f;
  for (int i=0;i<32;i++){
    uint4 v = p[(size_t)i*256 + t];
    float f0=blo(v.x),f1=bhi(v.x),f2=blo(v.y),f3=bhi(v.y);
    float f4=blo(v.z),f5=bhi(v.z),f6=blo(v.w),f7=bhi(v.w);
    s  += (f0+f1)+(f2+f3)+(f4+f5)+(f6+f7);
    ss += (f0*f0+f1*f1)+(f2*f2+f3*f3)+(f4*f4+f5*f5)+(f6*f6+f7*f7);
  }
  s = wred(s); ss = wred(ss);
  int lane = t&63, wid = t>>6;
  if (lane==0){ red[wid]=s; red[4+wid]=ss; }
  __syncthreads();
  if (t==0){
    float a=red[0]+red[1]+red[2]+red[3];
    float b=red[4]+red[5]+red[6]+red[7];
    float mu = a/65536.f; float var = b/65536.f - mu*mu;
    lnst[nn*2] = mu; lnst[nn*2+1] = rsqrtf(var + 1e-5f);
  }
}

// Apply LN + dn scale/shift, transposing (n,s,c) -> (n,c,h,w). Output dtype adaptive.
__global__ __launch_bounds__(256) void final_k(
    const u16* __restrict__ z, const float* __restrict__ lnst,
    const u16* __restrict__ dng, const u16* __restrict__ dnb,
    void* __restrict__ outp, const u32* __restrict__ probe)
{
  __shared__ float zt[32*257];
  const bool pf32 = probe_f32(probe);
  int b = blockIdx.x; int nn = b >> 3; int s0 = (b & 7)*32;
  int t = threadIdx.x;
  {
    int srow = t >> 3; int c0 = (t & 7)*32;
    const uint4* p = (const uint4*)(z + (size_t)nn*65536 + (size_t)(s0+srow)*256 + c0);
    float* dst = &zt[srow*257 + c0];
    #pragma unroll
    for (int i=0;i<4;i++){
      uint4 v = p[i];
      dst[i*8+0]=blo(v.x); dst[i*8+1]=bhi(v.x); dst[i*8+2]=blo(v.y); dst[i*8+3]=bhi(v.y);
      dst[i*8+4]=blo(v.z); dst[i*8+5]=bhi(v.z); dst[i*8+6]=blo(v.w); dst[i*8+7]=bhi(v.w);
    }
  }
  __syncthreads();
  float mu = lnst[nn*2], rs = lnst[nn*2+1];
  int sl = t & 31, cq = t >> 5;                    // cq in [0,8)
  for (int i=0;i<32;i++){
    int c = i*8 + cq;
    float v = (zt[sl*257 + c] - mu) * rs;
    int gidx = c*256 + s0 + sl;
    float res = v*b2f(dng[gidx]) + b2f(dnb[gidx]);
    size_t oi = (size_t)nn*65536 + gidx;
    if (pf32) ((float*)outp)[oi] = res;
    else      ((u16*)outp)[oi]   = f2b(res);
  }
}

// ---------------------------------------------------------------------------
extern "C" void kernel_launch(void* const* d_in, const int* in_sizes, int n_in,
                              void* d_out, int out_size, void* d_ws, size_t ws_size,
                              hipStream_t stream) {
  (void)in_sizes; (void)n_in; (void)out_size; (void)ws_size;
  const u32* probe = (const u32*)d_in[21];   // gn_g == ones

  // Canonical bf16 copies of small inputs (cvt region offsets, elems):
  char* w = (char*)d_ws;
  u16* cvt = (u16*)w;
  u16 *cWv  = cvt+0,       *cWo  = cvt+262144, *cWk1 = cvt+524288, *cWk2 = cvt+589824;
  u16 *cWpc = cvt+1179648, *cWf1 = cvt+1245184,*cWf2 = cvt+1310720;
  u16 *cdng = cvt+1376256, *cdnb = cvt+1441792,*cbu  = cvt+1507328;
  u16 *cbp  = cvt+1572864, *cbv  = cvt+1573376,*cbo  = cvt+1573888;
  u16 *cln1g= cvt+1574400, *cln1b= cvt+1574912,*cbk1 = cvt+1575424,*cbk2 = cvt+1575680;
  u16 *cbpc = cvt+1577984, *cgng = cvt+1578240,*cgnb = cvt+1578496;
  u16 *cbf1 = cvt+1578752, *cbf2 = cvt+1579008;

  float* tp_raw = (float*)(w + 4194304);   // 128x512 f32
  u16*   enh    = (u16*)  (w + 4456448);   // 128x512 bf16
  float* gapb   = (float*)(w + 4587520);   // 128x256 f32
  float* kernb  = (float*)(w + 4718592);   // 128x2304 f32
  float* gnst   = (float*)(w + 5898240);   // 128x32x2 f32
  float* lnst   = (float*)(w + 5931008);   // 128x2 f32
  u16*   fa     = (u16*)  (w + 8388608);   // 128x256x256 bf16 (n,c,s) 16MB
  u16*   out2   = (u16*)  (w + 25165824);  // 128x256x256 bf16 (n,s,c) 16MB
  u16*   z      = out2;                    // reuse after PW2 consumes out2
  u16*   dwb    = (u16*)d_out;             // d_out as scratch (dead until final_k)
  u16*   y1     = dwb;

  SrcTab st;
  st.p[0]=d_in[9];  st.p[1]=d_in[11]; st.p[2]=d_in[15]; st.p[3]=d_in[17];
  st.p[4]=d_in[19]; st.p[5]=d_in[23]; st.p[6]=d_in[25]; st.p[7]=d_in[27];
  st.p[8]=d_in[28]; st.p[9]=d_in[4];  st.p[10]=d_in[2]; st.p[11]=d_in[10];
  st.p[12]=d_in[12];st.p[13]=d_in[13];st.p[14]=d_in[14];st.p[15]=d_in[16];
  st.p[16]=d_in[18];st.p[17]=d_in[20];st.p[18]=d_in[21];st.p[19]=d_in[22];
  st.p[20]=d_in[24];st.p[21]=d_in[26];

  // 0) convert small inputs
  cvt_k<<<dim3(576,22), 256, 0, stream>>>(st, probe, cvt);
  // 1) tp = tokens @ Wp.T  (split-K, atomic f32; bias bp added in attn)
  // global_load_lds staging of raw f32/bf16 tiles; kchunk=1024, z=64 -> 1024 blocks.
  hipMemsetAsync(tp_raw, 0, 128*512*4, stream);
  gemm32_k<<<dim3(2,8,64), 256, 0, stream>>>(d_in[0], 65536, d_in[1], 65536, tp_raw,
      512, 1024, probe);
  // 2) attention + residual + LN -> enh
  attn_ln_k<<<128, 512, 0, stream>>>(tp_raw, cWv, cbv, cWo, cbo, cbp, cln1g, cln1b, enh);
  // 3) feat_attn = enh @ Wu.T + bu -> fa bf16 (n,c,s)
  gemm_k<1><<<dim3(2,1024,1), 256, 0, stream>>>(enh, 512, d_in[3], 512, fa,
      65536, 512, 0, cbu, nullptr, nullptr, nullptr, nullptr, probe, 0, 1);
  // 4) gap
  gap_k<<<8192, 256, 0, stream>>>(fa, gapb);
  // 5) hid/kern
  hidkern_k<<<128, 256, 0, stream>>>(gapb, cWk1, cbk1, cWk2, cbk2, kernb);
  // 6) dynamic depthwise 3x3 -> dwb bf16 (n,s,c) in d_out
  conv_k<<<2048, 256, 0, stream>>>(fa, kernb, dwb);
  // 7) out2 = dw @ Wpc.T + bpc
  gemm_k<1><<<dim3(512,4,1), 256, 0, stream>>>(dwb, 256, cWpc, 256, out2,
      256, 256, 0, cbpc, nullptr, nullptr, nullptr, nullptr, probe, 0, 0);
  // 8) GroupNorm stats
  gnstats_k<<<1024, 256, 0, stream>>>(out2, gnst);
  // 9) y1 = relu(GN(out2) @ Wf1.T + bf1)  (GN fused into A staging; y1 in d_out)
  gemm_k<3><<<dim3(512,4,1), 256, 0, stream>>>(out2, 256, cWf1, 256, y1,
      256, 256, 0, cbf1, gnst, cgng, cgnb, nullptr, probe, 0, 0);
  // 10) z = y1 @ Wf2.T + bf2 + feat_attn  (z overlays out2)
  gemm_k<4><<<dim3(512,4,1), 256, 0, stream>>>(y1, 256, cWf2, 256, z,
      256, 256, 0, cbf2, nullptr, nullptr, nullptr, fa, probe, 0, 0);
  // 11) final LN stats
  lnstats_k<<<128, 256, 0, stream>>>(z, lnst);
  // 12) LN * dn_g + dn_b, transpose to (n,c,h,w), adaptive out dtype
  final_k<<<1024, 256, 0, stream>>>(z, lnst, cdng, cdnb, d_out, probe);
}